// Round 3
// baseline (1028.924 us; speedup 1.0000x reference)
//
#include <hip/hip_runtime.h>

// EdgeModel: out = relu(cat[src(64),dest(64),edge(32)] @ w1[160,128] + b1) @ w2[128,32] + b2
// E = 1,600,000 rows, f32 in/out, bf16 MFMA (threshold 8.8e-2 >> ~3e-2 bf16 err).
//
// R3: R2's swapped-operand structure (h lane-local, no LDS round-trip) with
// SECTOR-CLEAN global access. Loads: f32x4 at rq*16 / 64+rq*16 -> every load
// instruction covers 16 full 64-B sectors (R2's rq*32+{0,16} pattern touched
// 64 sparse 16-B chunks -> 2.8x HBM over-fetch). The induced k-permutation is
// absorbed into the w1s fragment staging (MFMA k-slots are a free bijection,
// proven on-device in R2's GEMM2). Stores: GEMM2 operands swapped so each lane
// holds 4 consecutive out columns -> two f32x4 stores, 64-B sector-clean.

typedef float  f32x4  __attribute__((ext_vector_type(4)));
typedef short  s16x8  __attribute__((ext_vector_type(8)));

__device__ __forceinline__ unsigned short f2bf(float f) {
    // RTNE float -> bf16 bits
    unsigned int u = __float_as_uint(f);
    u += 0x7FFFu + ((u >> 16) & 1u);
    return (unsigned short)(u >> 16);
}

__global__ __launch_bounds__(512, 4) void edge_mlp(
    const float* __restrict__ src, const float* __restrict__ dst,
    const float* __restrict__ edg, const float* __restrict__ w1,
    const float* __restrict__ b1, const float* __restrict__ w2,
    const float* __restrict__ b2, float* __restrict__ out, int ntiles)
{
    // LDS: w1 fragments 40*64*16B = 40KB + b1 512B -> up to 3 blocks/CU.
    __shared__ __align__(16) unsigned short w1s[40 * 64 * 8];
    __shared__ __align__(16) float b1s[128];

    const int t    = threadIdx.x;
    const int lane = t & 63;
    const int wid  = t >> 6;      // 0..7
    const int rq   = lane >> 4;   // 0..3
    const int rr   = lane & 15;   // 0..15

    // ---- stage w1 into fragment-order LDS (once per block) ----
    // Slot bijection (must match the x-load pattern):
    //   frag-lane l = (q = l>>4, i = l&15), elem j ->
    //   k_local = (j<4 ? 0 : 16) + q*4 + (j&3),  hidden col = n*16 + i
    for (int s = t; s < 40 * 64; s += 512) {
        const int f  = s >> 6, l = s & 63;
        const int kk = f >> 3, n = f & 7;
        const int q  = l >> 4, i = l & 15;
        union { s16x8 v; unsigned short u[8]; } r;
#pragma unroll
        for (int j = 0; j < 8; ++j) {
            const int kl = ((j < 4) ? 0 : 16) + q * 4 + (j & 3);
            r.u[j] = f2bf(w1[(kk * 32 + kl) * 128 + n * 16 + i]);
        }
        *reinterpret_cast<s16x8*>(&w1s[s * 8]) = r.v;
    }
    if (t < 128) b1s[t] = b1[t];

    // ---- w2 fragments (A-operand, same slot bijection) + b2 ----
    // A row i = l&15 -> out col n2*16 + rr ; k = (j<4 ? m*16 : (m+4)*16) + rq*4 + (j&3)
    s16x8 w2f[4][2];
#pragma unroll
    for (int m = 0; m < 4; ++m)
#pragma unroll
        for (int n2 = 0; n2 < 2; ++n2) {
            union { s16x8 v; unsigned short u[8]; } r;
#pragma unroll
            for (int j = 0; j < 4; ++j) {
                r.u[j]     = f2bf(w2[(m * 16 + rq * 4 + j) * 32 + n2 * 16 + rr]);
                r.u[4 + j] = f2bf(w2[((m + 4) * 16 + rq * 4 + j) * 32 + n2 * 16 + rr]);
            }
            w2f[m][n2] = r.v;
        }
    // b2 init vectors: acc2[n2][j] = b2[n2*16 + rq*4 + j]
    const f32x4 b2r0 = *reinterpret_cast<const f32x4*>(b2 + rq * 4);
    const f32x4 b2r1 = *reinterpret_cast<const f32x4*>(b2 + 16 + rq * 4);

    __syncthreads();

    for (int tile = blockIdx.x; tile < ntiles; tile += gridDim.x) {
        const size_t row0 = (size_t)tile * 128 + (size_t)wid * 16;

        // ---- GEMM1 (swapped): acc[n][j] = h_pre[row0+rr][n*16 + rq*4 + j] ----
        f32x4 acc[8];
#pragma unroll
        for (int n = 0; n < 8; ++n)
            acc[n] = *reinterpret_cast<const f32x4*>(&b1s[n * 16 + rq * 4]);

#pragma unroll
        for (int kk = 0; kk < 5; ++kk) {
            const float* sp; int cols, cofs;
            if      (kk == 0) { sp = src; cols = 64; cofs = 0;  }
            else if (kk == 1) { sp = src; cols = 64; cofs = 32; }
            else if (kk == 2) { sp = dst; cols = 64; cofs = 0;  }
            else if (kk == 3) { sp = dst; cols = 64; cofs = 32; }
            else              { sp = edg; cols = 32; cofs = 0;  }

            // Sector-clean loads: instruction footprint = 16 rows x 64 B contiguous.
            // v0 -> k_local = rq*4 + j ; v1 -> k_local = 16 + rq*4 + j
            const float* p = sp + (row0 + rr) * (size_t)cols + cofs;
            f32x4 v0 = *reinterpret_cast<const f32x4*>(p + rq * 4);
            f32x4 v1 = *reinterpret_cast<const f32x4*>(p + 16 + rq * 4);
            union { s16x8 v; unsigned short u[8]; } a;
#pragma unroll
            for (int j = 0; j < 4; ++j) {
                a.u[j]     = f2bf(v0[j]);
                a.u[4 + j] = f2bf(v1[j]);
            }

#pragma unroll
            for (int n = 0; n < 8; ++n) {
                s16x8 wv = *reinterpret_cast<const s16x8*>(&w1s[((kk * 8 + n) * 64 + lane) * 8]);
                acc[n] = __builtin_amdgcn_mfma_f32_16x16x32_bf16(wv, a.v, acc[n], 0, 0, 0);
            }
        }

        // ---- GEMM2: relu+cvt lane-local; A=w2f so D gives 4 consecutive out cols ----
        f32x4 acc2[2] = {b2r0, b2r1};

#pragma unroll
        for (int m = 0; m < 4; ++m) {
            union { s16x8 v; unsigned short u[8]; } hh;
#pragma unroll
            for (int j = 0; j < 4; ++j) {
                hh.u[j]     = f2bf(fmaxf(acc[m][j], 0.0f));      // k chunk m
                hh.u[4 + j] = f2bf(fmaxf(acc[m + 4][j], 0.0f));  // k chunk m+4
            }
            acc2[0] = __builtin_amdgcn_mfma_f32_16x16x32_bf16(w2f[m][0], hh.v, acc2[0], 0, 0, 0);
            acc2[1] = __builtin_amdgcn_mfma_f32_16x16x32_bf16(w2f[m][1], hh.v, acc2[1], 0, 0, 0);
        }

        // store: lane (rq,rr) holds out[row0+rr][n2*16 + rq*4 .. +3] -> f32x4,
        // instruction footprint = 16 rows x 64-B sectors, both halves adjacent.
        float* po = out + (row0 + rr) * 32;
        *reinterpret_cast<f32x4*>(po + rq * 4)      = acc2[0];
        *reinterpret_cast<f32x4*>(po + 16 + rq * 4) = acc2[1];
    }
}

// Scalar tail for E % 128 != 0 (not hit for E = 1,600,000; kept for safety)
__global__ void edge_mlp_tail(
    const float* __restrict__ src, const float* __restrict__ dst,
    const float* __restrict__ edg, const float* __restrict__ w1,
    const float* __restrict__ b1, const float* __restrict__ w2,
    const float* __restrict__ b2, float* __restrict__ out,
    long long row0, long long E)
{
    const long long r = row0 + blockIdx.x;
    if (r >= E) return;
    __shared__ float h[128];
    const int t = threadIdx.x;  // 128 threads
    float acc = b1[t];
    for (int k = 0; k < 64; ++k) acc += src[r * 64 + k] * w1[k * 128 + t];
    for (int k = 0; k < 64; ++k) acc += dst[r * 64 + k] * w1[(64 + k) * 128 + t];
    for (int k = 0; k < 32; ++k) acc += edg[r * 32 + k] * w1[(128 + k) * 128 + t];
    h[t] = acc > 0.0f ? acc : 0.0f;
    __syncthreads();
    if (t < 32) {
        float o = b2[t];
        for (int k = 0; k < 128; ++k) o += h[k] * w2[k * 32 + t];
        out[r * 32 + t] = o;
    }
}

extern "C" void kernel_launch(void* const* d_in, const int* in_sizes, int n_in,
                              void* d_out, int out_size, void* d_ws, size_t ws_size,
                              hipStream_t stream)
{
    const float* src = (const float*)d_in[0];
    const float* dst = (const float*)d_in[1];
    const float* edg = (const float*)d_in[2];
    // d_in[3] = u (unused), d_in[4] = batch (unused)
    const float* w1  = (const float*)d_in[5];
    const float* b1  = (const float*)d_in[6];
    const float* w2  = (const float*)d_in[7];
    const float* b2  = (const float*)d_in[8];
    float* out = (float*)d_out;

    const long long E      = (long long)in_sizes[0] / 64;
    const int       ntiles = (int)(E / 128);
    const long long rem    = E - (long long)ntiles * 128;

    if (ntiles > 0) {
        int grid = ntiles < 768 ? ntiles : 768;
        edge_mlp<<<dim3(grid), dim3(512), 0, stream>>>(
            src, dst, edg, w1, b1, w2, b2, out, ntiles);
    }
    if (rem > 0) {
        edge_mlp_tail<<<dim3((unsigned)rem), dim3(128), 0, stream>>>(
            src, dst, edg, w1, b1, w2, b2, out, (long long)ntiles * 128, E);
    }
}

// Round 4
// 649.647 us; speedup vs baseline: 1.5838x; 1.5838x over previous
//
#include <hip/hip_runtime.h>

// EdgeModel: out = relu(cat[src(64),dest(64),edge(32)] @ w1[160,128] + b1) @ w2[128,32] + b2
// E = 1,600,000 rows, f32 in/out, bf16 MFMA (threshold 8.8e-2 >> ~3e-2 bf16 err).
//
// R4 = R1 exactly (256-thr blocks, 4 waves, 32-row windows via rf loop, R1's load
// and store byte patterns, R1's w1s staging) with two changes:
//  (a) GEMM1 operand-swapped: mfma(w1frag, xfrag) -> h lane-local -> hbuf GEMM2
//      replaced by R2's register-only slot-bijection GEMM2 (D layout == R1 store).
//  (b) LDS 57->40.5 KB, grid 512->768 -> 3 blocks/CU (12 waves/CU, +50% vs R1).
// Bisect intent: R1 traffic was clean (FETCH 0.5GB, WRITE 1.0x); R2/R3's 512-thr
// config inflated traffic 2.2-2.6x with equivalent per-instruction patterns.

typedef float  f32x4  __attribute__((ext_vector_type(4)));
typedef short  s16x8  __attribute__((ext_vector_type(8)));

__device__ __forceinline__ unsigned short f2bf(float f) {
    // RTNE float -> bf16 bits
    unsigned int u = __float_as_uint(f);
    u += 0x7FFFu + ((u >> 16) & 1u);
    return (unsigned short)(u >> 16);
}

__global__ __launch_bounds__(256, 3) void edge_mlp(
    const float* __restrict__ src, const float* __restrict__ dst,
    const float* __restrict__ edg, const float* __restrict__ w1,
    const float* __restrict__ b1, const float* __restrict__ w2,
    const float* __restrict__ b2, float* __restrict__ out, int ntiles)
{
    // LDS: w1 fragments 40*64*16B = 40KB + b1 512B -> 3 blocks/CU.
    __shared__ __align__(16) unsigned short w1s[40 * 64 * 8];
    __shared__ __align__(16) float b1s[128];

    const int t    = threadIdx.x;
    const int lane = t & 63;
    const int wid  = t >> 6;      // 0..3
    const int rq   = lane >> 4;   // 0..3
    const int rr   = lane & 15;   // 0..15

    // ---- stage w1 into fragment-order LDS (R1's exact staging) ----
    // frag f = kk*8+n ; lane l elem j = w1[kk*32 + (l>>4)*8 + j][n*16 + (l&15)]
    // As swapped-GEMM1 A-operand: A[row = l&15 = hid sub-col][k = (l>>4)*8 + j].
    for (int s = t; s < 40 * 64; s += 256) {
        const int f  = s >> 6, l = s & 63;
        const int kk = f >> 3, n = f & 7;
        const int k0 = kk * 32 + ((l >> 4) << 3);
        const int cl = (n << 4) + (l & 15);
        union { s16x8 v; unsigned short u[8]; } r;
#pragma unroll
        for (int j = 0; j < 8; ++j)
            r.u[j] = f2bf(w1[(k0 + j) * 128 + cl]);
        *reinterpret_cast<s16x8*>(&w1s[s * 8]) = r.v;
    }
    if (t < 128) b1s[t] = b1[t];

    // ---- w2 fragments (B-operand, slot bijection matching hh) + b2 ----
    // slot (rq, j): logical k = (j<4 ? m*16 : (m+4)*16) + rq*4 + (j&3); col = rr.
    s16x8 w2f[4][2];
#pragma unroll
    for (int m = 0; m < 4; ++m)
#pragma unroll
        for (int n2 = 0; n2 < 2; ++n2) {
            union { s16x8 v; unsigned short u[8]; } r;
#pragma unroll
            for (int j = 0; j < 4; ++j) {
                r.u[j]     = f2bf(w2[(m * 16 + rq * 4 + j) * 32 + n2 * 16 + rr]);
                r.u[4 + j] = f2bf(w2[((m + 4) * 16 + rq * 4 + j) * 32 + n2 * 16 + rr]);
            }
            w2f[m][n2] = r.v;
        }
    const float b2c0 = b2[rr];
    const float b2c1 = b2[16 + rr];

    __syncthreads();

    for (int tile = blockIdx.x; tile < ntiles; tile += gridDim.x) {
        const size_t base = (size_t)tile * 128 + (size_t)wid * 32;

        // ---- GEMM1 (swapped): acc[rf][n][j] = h[base+rf*16+rr][n*16+rq*4+j] ----
        f32x4 acc[2][8];
#pragma unroll
        for (int rf = 0; rf < 2; ++rf)
#pragma unroll
            for (int n = 0; n < 8; ++n)
                acc[rf][n] = *reinterpret_cast<const f32x4*>(&b1s[n * 16 + rq * 4]);

#pragma unroll
        for (int kk = 0; kk < 5; ++kk) {
            const float* sp; int cols, cofs;
            if      (kk == 0) { sp = src; cols = 64; cofs = 0;  }
            else if (kk == 1) { sp = src; cols = 64; cofs = 32; }
            else if (kk == 2) { sp = dst; cols = 64; cofs = 0;  }
            else if (kk == 3) { sp = dst; cols = 64; cofs = 32; }
            else              { sp = edg; cols = 32; cofs = 0;  }

            // R1's exact load construction (B-operand: col = rr, k = rq*8 + j)
            s16x8 a[2];
#pragma unroll
            for (int rf = 0; rf < 2; ++rf) {
                const float* p = sp + (base + rf * 16 + rr) * (size_t)cols + cofs + (rq << 3);
                f32x4 v0 = *reinterpret_cast<const f32x4*>(p);
                f32x4 v1 = *reinterpret_cast<const f32x4*>(p + 4);
                union { s16x8 v; unsigned short u[8]; } r;
                r.u[0] = f2bf(v0.x); r.u[1] = f2bf(v0.y);
                r.u[2] = f2bf(v0.z); r.u[3] = f2bf(v0.w);
                r.u[4] = f2bf(v1.x); r.u[5] = f2bf(v1.y);
                r.u[6] = f2bf(v1.z); r.u[7] = f2bf(v1.w);
                a[rf] = r.v;
            }
#pragma unroll
            for (int n = 0; n < 8; ++n) {
                s16x8 wv = *reinterpret_cast<const s16x8*>(&w1s[((kk * 8 + n) * 64 + lane) * 8]);
                acc[0][n] = __builtin_amdgcn_mfma_f32_16x16x32_bf16(wv, a[0], acc[0][n], 0, 0, 0);
                acc[1][n] = __builtin_amdgcn_mfma_f32_16x16x32_bf16(wv, a[1], acc[1][n], 0, 0, 0);
            }
        }

        // ---- GEMM2: register-only, slot-bijection; D layout == R1's store ----
#pragma unroll
        for (int rf = 0; rf < 2; ++rf) {
            f32x4 acc2[2];
            acc2[0] = (f32x4){b2c0, b2c0, b2c0, b2c0};
            acc2[1] = (f32x4){b2c1, b2c1, b2c1, b2c1};

#pragma unroll
            for (int m = 0; m < 4; ++m) {
                union { s16x8 v; unsigned short u[8]; } hh;
#pragma unroll
                for (int j = 0; j < 4; ++j) {
                    hh.u[j]     = f2bf(fmaxf(acc[rf][m][j], 0.0f));      // k chunk m
                    hh.u[4 + j] = f2bf(fmaxf(acc[rf][m + 4][j], 0.0f));  // k chunk m+4
                }
                acc2[0] = __builtin_amdgcn_mfma_f32_16x16x32_bf16(hh.v, w2f[m][0], acc2[0], 0, 0, 0);
                acc2[1] = __builtin_amdgcn_mfma_f32_16x16x32_bf16(hh.v, w2f[m][1], acc2[1], 0, 0, 0);
            }

            // R1's exact store: D row = rq*4+j (edge row), col = n2*16+rr
#pragma unroll
            for (int n2 = 0; n2 < 2; ++n2)
#pragma unroll
                for (int j = 0; j < 4; ++j) {
                    const size_t row = base + rf * 16 + rq * 4 + j;
                    out[row * 32 + n2 * 16 + rr] = (n2 == 0 ? acc2[0][j] : acc2[1][j]);
                }
        }
    }
}

// Scalar tail for E % 128 != 0 (not hit for E = 1,600,000; kept for safety)
__global__ void edge_mlp_tail(
    const float* __restrict__ src, const float* __restrict__ dst,
    const float* __restrict__ edg, const float* __restrict__ w1,
    const float* __restrict__ b1, const float* __restrict__ w2,
    const float* __restrict__ b2, float* __restrict__ out,
    long long row0, long long E)
{
    const long long r = row0 + blockIdx.x;
    if (r >= E) return;
    __shared__ float h[128];
    const int t = threadIdx.x;  // 128 threads
    float acc = b1[t];
    for (int k = 0; k < 64; ++k) acc += src[r * 64 + k] * w1[k * 128 + t];
    for (int k = 0; k < 64; ++k) acc += dst[r * 64 + k] * w1[(64 + k) * 128 + t];
    for (int k = 0; k < 32; ++k) acc += edg[r * 32 + k] * w1[(128 + k) * 128 + t];
    h[t] = acc > 0.0f ? acc : 0.0f;
    __syncthreads();
    if (t < 32) {
        float o = b2[t];
        for (int k = 0; k < 128; ++k) o += h[k] * w2[k * 32 + t];
        out[r * 32 + t] = o;
    }
}

extern "C" void kernel_launch(void* const* d_in, const int* in_sizes, int n_in,
                              void* d_out, int out_size, void* d_ws, size_t ws_size,
                              hipStream_t stream)
{
    const float* src = (const float*)d_in[0];
    const float* dst = (const float*)d_in[1];
    const float* edg = (const float*)d_in[2];
    // d_in[3] = u (unused), d_in[4] = batch (unused)
    const float* w1  = (const float*)d_in[5];
    const float* b1  = (const float*)d_in[6];
    const float* w2  = (const float*)d_in[7];
    const float* b2  = (const float*)d_in[8];
    float* out = (float*)d_out;

    const long long E      = (long long)in_sizes[0] / 64;
    const int       ntiles = (int)(E / 128);
    const long long rem    = E - (long long)ntiles * 128;

    if (ntiles > 0) {
        int grid = ntiles < 768 ? ntiles : 768;
        edge_mlp<<<dim3(grid), dim3(256), 0, stream>>>(
            src, dst, edg, w1, b1, w2, b2, out, ntiles);
    }
    if (rem > 0) {
        edge_mlp_tail<<<dim3((unsigned)rem), dim3(128), 0, stream>>>(
            src, dst, edg, w1, b1, w2, b2, out, (long long)ntiles * 128, E);
    }
}

// Round 5
// 469.056 us; speedup vs baseline: 2.1936x; 1.3850x over previous
//
#include <hip/hip_runtime.h>

// EdgeModel: out = relu(cat[src(64),dest(64),edge(32)] @ w1[160,128] + b1) @ w2[128,32] + b2
// E = 1,600,000 rows, f32 in/out, bf16 MFMA (threshold 8.8e-2 >> ~3e-2 bf16 err).
//
// R5: fix HBM over-fetch by making every cache line consumed by EXACTLY ONE
// instruction. R2-R4 split each 128-B line across two sparse loads (v0/v1);
// under 12-16 waves/CU the line was evicted between them -> 1.9-2.8x refetch.
// Now: fully-coalesced f32x4 loads (lane l -> base + l*16; one instruction =
// 1024 contiguous B = 8 whole lines), bf16-convert in reg, stage to a
// WAVE-PRIVATE padded LDS tile (no barriers in main loop), ds_read_b128 the
// MFMA fragments from LDS. Padded strides (144/80 B) give the optimal
// 2-lanes-per-bank-quad for b128. w1s staging + GEMM1 math = R4 (verified);
// GEMM2 + f32x4 stores = R3 (verified).

typedef float  f32x4  __attribute__((ext_vector_type(4)));
typedef short  s16x8  __attribute__((ext_vector_type(8)));
typedef unsigned short u16x4 __attribute__((ext_vector_type(4)));

#define SRC_STRIDE 144               // LDS bytes per 64-col bf16 row (128 + 16 pad)
#define EDG_STRIDE 80                // LDS bytes per 32-col bf16 row (64 + 16 pad)
#define WS_BYTES   (32 * SRC_STRIDE + 16 * EDG_STRIDE)   // 4608+4608... = 2*2304 + 1280 = 5888

__device__ __forceinline__ unsigned short f2bf(float f) {
    // RTNE float -> bf16 bits
    unsigned int u = __float_as_uint(f);
    u += 0x7FFFu + ((u >> 16) & 1u);
    return (unsigned short)(u >> 16);
}

__global__ __launch_bounds__(256, 2) void edge_mlp(
    const float* __restrict__ src, const float* __restrict__ dst,
    const float* __restrict__ edg, const float* __restrict__ w1,
    const float* __restrict__ b1, const float* __restrict__ w2,
    const float* __restrict__ b2, float* __restrict__ out, int ntiles)
{
    // LDS: w1 frags 40960 + b1 512 + 4 wave-private x tiles 4*5888 = 65024 B
    // -> 2 blocks/CU (160 KB), 8 waves/CU.
    __shared__ __align__(16) unsigned short w1s[40 * 64 * 8];
    __shared__ __align__(16) float b1s[128];
    __shared__ __align__(16) char xs[4][WS_BYTES];

    const int t    = threadIdx.x;
    const int lane = t & 63;
    const int wid  = t >> 6;      // 0..3
    const int rq   = lane >> 4;   // 0..3
    const int rr   = lane & 15;   // 0..15

    // ---- stage w1 into fragment-order LDS (R4's exact staging; verified) ----
    // frag f = kk*8+n ; lane l elem j = w1[kk*32 + (l>>4)*8 + j][n*16 + (l&15)]
    for (int s = t; s < 40 * 64; s += 256) {
        const int f  = s >> 6, l = s & 63;
        const int kk = f >> 3, n = f & 7;
        const int k0 = kk * 32 + ((l >> 4) << 3);
        const int cl = (n << 4) + (l & 15);
        union { s16x8 v; unsigned short u[8]; } r;
#pragma unroll
        for (int j = 0; j < 8; ++j)
            r.u[j] = f2bf(w1[(k0 + j) * 128 + cl]);
        *reinterpret_cast<s16x8*>(&w1s[s * 8]) = r.v;
    }
    if (t < 128) b1s[t] = b1[t];

    // ---- w2 fragments (R3's A-operand build; verified) + b2 ----
    s16x8 w2f[4][2];
#pragma unroll
    for (int m = 0; m < 4; ++m)
#pragma unroll
        for (int n2 = 0; n2 < 2; ++n2) {
            union { s16x8 v; unsigned short u[8]; } r;
#pragma unroll
            for (int j = 0; j < 4; ++j) {
                r.u[j]     = f2bf(w2[(m * 16 + rq * 4 + j) * 32 + n2 * 16 + rr]);
                r.u[4 + j] = f2bf(w2[((m + 4) * 16 + rq * 4 + j) * 32 + n2 * 16 + rr]);
            }
            w2f[m][n2] = r.v;
        }
    const f32x4 b2r0 = *reinterpret_cast<const f32x4*>(b2 + rq * 4);
    const f32x4 b2r1 = *reinterpret_cast<const f32x4*>(b2 + 16 + rq * 4);

    __syncthreads();

    char* const wsS = xs[wid];                      // src tile: 16 rows x 144 B
    char* const wsD = xs[wid] + 16 * SRC_STRIDE;    // dst tile: 16 rows x 144 B
    char* const wsE = xs[wid] + 32 * SRC_STRIDE;    // edg tile: 16 rows x 80 B

    const int srow  = lane >> 4;          // staging sub-row (src/dst)
    const int scol8 = (lane & 15) * 8;    // staging byte col (src/dst)
    const int erow  = lane >> 3;          // staging sub-row (edge)
    const int ecol8 = (lane & 7) * 8;     // staging byte col (edge)

    for (int tile = blockIdx.x; tile < ntiles; tile += gridDim.x) {
        const size_t row0 = (size_t)tile * 64 + (size_t)wid * 16;

        // ---- coalesced loads: lane l reads [base + l*16, +16) ----
        // one instruction = 1024 contiguous bytes = 8 full lines, consumed once.
        const float* gs = src + row0 * 64;
        const float* gd = dst + row0 * 64;
        const float* ge = edg + row0 * 32;
        f32x4 ls[4], ld[4], le[2];
#pragma unroll
        for (int i = 0; i < 4; ++i) ls[i] = *reinterpret_cast<const f32x4*>(gs + i * 256 + lane * 4);
#pragma unroll
        for (int i = 0; i < 4; ++i) ld[i] = *reinterpret_cast<const f32x4*>(gd + i * 256 + lane * 4);
#pragma unroll
        for (int i = 0; i < 2; ++i) le[i] = *reinterpret_cast<const f32x4*>(ge + i * 256 + lane * 4);

        // ---- bf16-convert + wave-private LDS stage (no barrier needed) ----
#pragma unroll
        for (int i = 0; i < 4; ++i) {
            u16x4 p = {f2bf(ls[i].x), f2bf(ls[i].y), f2bf(ls[i].z), f2bf(ls[i].w)};
            *reinterpret_cast<u16x4*>(wsS + (i * 4 + srow) * SRC_STRIDE + scol8) = p;
        }
#pragma unroll
        for (int i = 0; i < 4; ++i) {
            u16x4 p = {f2bf(ld[i].x), f2bf(ld[i].y), f2bf(ld[i].z), f2bf(ld[i].w)};
            *reinterpret_cast<u16x4*>(wsD + (i * 4 + srow) * SRC_STRIDE + scol8) = p;
        }
#pragma unroll
        for (int i = 0; i < 2; ++i) {
            u16x4 p = {f2bf(le[i].x), f2bf(le[i].y), f2bf(le[i].z), f2bf(le[i].w)};
            *reinterpret_cast<u16x4*>(wsE + (i * 8 + erow) * EDG_STRIDE + ecol8) = p;
        }

        // ---- GEMM1 (swapped): acc[n][j] = h[row0+rr][n*16+rq*4+j], bias-init ----
        f32x4 acc[8];
#pragma unroll
        for (int n = 0; n < 8; ++n)
            acc[n] = *reinterpret_cast<const f32x4*>(&b1s[n * 16 + rq * 4]);

#pragma unroll
        for (int kk = 0; kk < 5; ++kk) {
            // B-frag from LDS: lane (rq,rr) -> row rr, k = rq*8 + j (R4 bijection)
            const char* xb; int koff, strd;
            if      (kk == 0) { xb = wsS; koff = 0;  strd = SRC_STRIDE; }
            else if (kk == 1) { xb = wsS; koff = 64; strd = SRC_STRIDE; }
            else if (kk == 2) { xb = wsD; koff = 0;  strd = SRC_STRIDE; }
            else if (kk == 3) { xb = wsD; koff = 64; strd = SRC_STRIDE; }
            else              { xb = wsE; koff = 0;  strd = EDG_STRIDE; }
            s16x8 a = *reinterpret_cast<const s16x8*>(xb + rr * strd + koff + rq * 16);

#pragma unroll
            for (int n = 0; n < 8; ++n) {
                s16x8 wv = *reinterpret_cast<const s16x8*>(&w1s[((kk * 8 + n) * 64 + lane) * 8]);
                acc[n] = __builtin_amdgcn_mfma_f32_16x16x32_bf16(wv, a, acc[n], 0, 0, 0);
            }
        }

        // ---- GEMM2 (R3's verified block): register-only, slot bijection ----
        f32x4 acc2[2] = {b2r0, b2r1};
#pragma unroll
        for (int m = 0; m < 4; ++m) {
            union { s16x8 v; unsigned short u[8]; } hh;
#pragma unroll
            for (int j = 0; j < 4; ++j) {
                hh.u[j]     = f2bf(fmaxf(acc[m][j], 0.0f));      // k chunk m
                hh.u[4 + j] = f2bf(fmaxf(acc[m + 4][j], 0.0f));  // k chunk m+4
            }
            acc2[0] = __builtin_amdgcn_mfma_f32_16x16x32_bf16(w2f[m][0], hh.v, acc2[0], 0, 0, 0);
            acc2[1] = __builtin_amdgcn_mfma_f32_16x16x32_bf16(w2f[m][1], hh.v, acc2[1], 0, 0, 0);
        }

        // ---- store (R3's verified layout): lane (rq,rr) -> out[row0+rr][rq*4..] ----
        float* po = out + (row0 + rr) * 32;
        *reinterpret_cast<f32x4*>(po + rq * 4)      = acc2[0];
        *reinterpret_cast<f32x4*>(po + 16 + rq * 4) = acc2[1];
    }
}

// Scalar tail for E % 64 != 0 (not hit for E = 1,600,000; kept for safety)
__global__ void edge_mlp_tail(
    const float* __restrict__ src, const float* __restrict__ dst,
    const float* __restrict__ edg, const float* __restrict__ w1,
    const float* __restrict__ b1, const float* __restrict__ w2,
    const float* __restrict__ b2, float* __restrict__ out,
    long long row0, long long E)
{
    const long long r = row0 + blockIdx.x;
    if (r >= E) return;
    __shared__ float h[128];
    const int t = threadIdx.x;  // 128 threads
    float acc = b1[t];
    for (int k = 0; k < 64; ++k) acc += src[r * 64 + k] * w1[k * 128 + t];
    for (int k = 0; k < 64; ++k) acc += dst[r * 64 + k] * w1[(64 + k) * 128 + t];
    for (int k = 0; k < 32; ++k) acc += edg[r * 32 + k] * w1[(128 + k) * 128 + t];
    h[t] = acc > 0.0f ? acc : 0.0f;
    __syncthreads();
    if (t < 32) {
        float o = b2[t];
        for (int k = 0; k < 128; ++k) o += h[k] * w2[k * 32 + t];
        out[r * 32 + t] = o;
    }
}

extern "C" void kernel_launch(void* const* d_in, const int* in_sizes, int n_in,
                              void* d_out, int out_size, void* d_ws, size_t ws_size,
                              hipStream_t stream)
{
    const float* src = (const float*)d_in[0];
    const float* dst = (const float*)d_in[1];
    const float* edg = (const float*)d_in[2];
    // d_in[3] = u (unused), d_in[4] = batch (unused)
    const float* w1  = (const float*)d_in[5];
    const float* b1  = (const float*)d_in[6];
    const float* w2  = (const float*)d_in[7];
    const float* b2  = (const float*)d_in[8];
    float* out = (float*)d_out;

    const long long E      = (long long)in_sizes[0] / 64;
    const int       ntiles = (int)(E / 64);
    const long long rem    = E - (long long)ntiles * 64;

    if (ntiles > 0) {
        int grid = ntiles < 512 ? ntiles : 512;
        edge_mlp<<<dim3(grid), dim3(256), 0, stream>>>(
            src, dst, edg, w1, b1, w2, b2, out, ntiles);
    }
    if (rem > 0) {
        edge_mlp_tail<<<dim3((unsigned)rem), dim3(128), 0, stream>>>(
            src, dst, edg, w1, b1, w2, b2, out, (long long)ntiles * 64, E);
    }
}

// Round 6
// 255.295 us; speedup vs baseline: 4.0303x; 1.8373x over previous
//
#include <hip/hip_runtime.h>

// EdgeModel: out = relu(cat[src(64),dest(64),edge(32)] @ w1[160,128] + b1) @ w2[128,32] + b2
// E = 1,600,000 rows, f32 in/out, bf16 MFMA (threshold 8.8e-2 >> ~3e-2 bf16 err).
//
// R6: R5 proved the traffic model (FETCH 0.93x compulsory). Remaining problem is
// per-wave latency: T_wave ~ 23k cycles because the compiler serialized the 10
// global loads (load->wait->use chains at the VGPR=128 cliff).
// Fix (a): inline-asm block issues all 10 global_load_dwordx4 back-to-back with
//          ONE s_waitcnt vmcnt(0) -> ~900 cy total instead of ~10x serial.
// Fix (b): 1024-thr blocks (16 waves) share one w1s; LDS=145,920 B, 1 block/CU
//          = 16 waves/CU (4/SIMD, 2x R5). w2 frags + b2 demoted to LDS so
//          VGPR stays <= 128 (required for 16-wave residency).
// Everything else (w1s staging, GEMM1 swapped-operand math, GEMM2 slot
// bijection, f32x4 stores, wave-private padded x tiles) is R5-verified.

typedef float  f32x4  __attribute__((ext_vector_type(4)));
typedef short  s16x8  __attribute__((ext_vector_type(8)));
typedef unsigned short u16x4 __attribute__((ext_vector_type(4)));

#define SRC_STRIDE 144               // LDS bytes per 64-col bf16 row (128 + 16 pad)
#define EDG_STRIDE 80                // LDS bytes per 32-col bf16 row (64 + 16 pad)
#define WS_BYTES   (32 * SRC_STRIDE + 16 * EDG_STRIDE)   // 5888 B per wave

__device__ __forceinline__ unsigned short f2bf(float f) {
    // RTNE float -> bf16 bits
    unsigned int u = __float_as_uint(f);
    u += 0x7FFFu + ((u >> 16) & 1u);
    return (unsigned short)(u >> 16);
}

__global__ __launch_bounds__(1024, 1) void edge_mlp(
    const float* __restrict__ src, const float* __restrict__ dst,
    const float* __restrict__ edg, const float* __restrict__ w1,
    const float* __restrict__ b1, const float* __restrict__ w2,
    const float* __restrict__ b2, float* __restrict__ out, int ntiles)
{
    // LDS: w1s 40960 + b1s 512 + w2s 8192 + b2s 2048 + xs 16*5888 = 145,920 B
    // -> 1 block/CU, 16 waves/CU (4 waves/SIMD, 50% occupancy).
    __shared__ __align__(16) unsigned short w1s[40 * 64 * 8];
    __shared__ __align__(16) float b1s[128];
    __shared__ __align__(16) unsigned short w2s[8 * 64 * 8];   // frag (m,n2) at ((m*2+n2)*64+lane)*8
    __shared__ __align__(16) float b2s[2 * 64 * 4];            // f32x4 per lane per n2
    __shared__ __align__(16) char xs[16][WS_BYTES];

    const int t    = threadIdx.x;
    const int lane = t & 63;
    const int wid  = t >> 6;      // 0..15
    const int rq   = lane >> 4;   // 0..3
    const int rr   = lane & 15;   // 0..15

    // ---- stage w1 into fragment-order LDS (R5-verified layout) ----
    // frag f = kk*8+n ; lane l elem j = w1[kk*32 + (l>>4)*8 + j][n*16 + (l&15)]
    for (int s = t; s < 40 * 64; s += 1024) {
        const int f  = s >> 6, l = s & 63;
        const int kk = f >> 3, n = f & 7;
        const int k0 = kk * 32 + ((l >> 4) << 3);
        const int cl = (n << 4) + (l & 15);
        union { s16x8 v; unsigned short u[8]; } r;
#pragma unroll
        for (int j = 0; j < 8; ++j)
            r.u[j] = f2bf(w1[(k0 + j) * 128 + cl]);
        *reinterpret_cast<s16x8*>(&w1s[s * 8]) = r.v;
    }
    if (t < 128) b1s[t] = b1[t];

    // ---- w2 fragments + b2 vectors -> LDS (wave 0 only; keeps VGPR low) ----
    if (wid == 0) {
#pragma unroll
        for (int m = 0; m < 4; ++m)
#pragma unroll
            for (int n2 = 0; n2 < 2; ++n2) {
                union { s16x8 v; unsigned short u[8]; } r;
#pragma unroll
                for (int j = 0; j < 4; ++j) {
                    r.u[j]     = f2bf(w2[(m * 16 + rq * 4 + j) * 32 + n2 * 16 + rr]);
                    r.u[4 + j] = f2bf(w2[((m + 4) * 16 + rq * 4 + j) * 32 + n2 * 16 + rr]);
                }
                *reinterpret_cast<s16x8*>(&w2s[((m * 2 + n2) * 64 + lane) * 8]) = r.v;
            }
        *reinterpret_cast<f32x4*>(&b2s[(0 * 64 + lane) * 4]) =
            *reinterpret_cast<const f32x4*>(b2 + rq * 4);
        *reinterpret_cast<f32x4*>(&b2s[(1 * 64 + lane) * 4]) =
            *reinterpret_cast<const f32x4*>(b2 + 16 + rq * 4);
    }

    __syncthreads();

    char* const wsS = xs[wid];                      // src tile: 16 rows x 144 B
    char* const wsD = xs[wid] + 16 * SRC_STRIDE;    // dst tile: 16 rows x 144 B
    char* const wsE = xs[wid] + 32 * SRC_STRIDE;    // edg tile: 16 rows x 80 B

    const int srow  = lane >> 4;          // staging sub-row (src/dst)
    const int scol8 = (lane & 15) * 8;    // staging byte col (src/dst)
    const int erow  = lane >> 3;          // staging sub-row (edge)
    const int ecol8 = (lane & 7) * 8;     // staging byte col (edge)

    for (int tile = blockIdx.x; tile < ntiles; tile += gridDim.x) {
        const size_t row0 = (size_t)tile * 256 + (size_t)wid * 16;

        // ---- all 10 coalesced loads issued back-to-back, ONE vmcnt(0) ----
        // lane l covers [base + l*16, +16); each instruction = 1024 contiguous B
        // = 8 whole cache lines, each line consumed by exactly one instruction.
        const float* gs = src + row0 * 64 + lane * 4;
        const float* gd = dst + row0 * 64 + lane * 4;
        const float* ge = edg + row0 * 32 + lane * 4;
        f32x4 s0v, s1v, s2v, s3v, d0v, d1v, d2v, d3v, e0v, e1v;
        asm volatile(
            "global_load_dwordx4 %[s0], %[ps], off\n\t"
            "global_load_dwordx4 %[s1], %[ps], off offset:1024\n\t"
            "global_load_dwordx4 %[s2], %[ps], off offset:2048\n\t"
            "global_load_dwordx4 %[s3], %[ps], off offset:3072\n\t"
            "global_load_dwordx4 %[d0], %[pd], off\n\t"
            "global_load_dwordx4 %[d1], %[pd], off offset:1024\n\t"
            "global_load_dwordx4 %[d2], %[pd], off offset:2048\n\t"
            "global_load_dwordx4 %[d3], %[pd], off offset:3072\n\t"
            "global_load_dwordx4 %[e0], %[pe], off\n\t"
            "global_load_dwordx4 %[e1], %[pe], off offset:1024\n\t"
            "s_waitcnt vmcnt(0)"
            : [s0]"=&v"(s0v), [s1]"=&v"(s1v), [s2]"=&v"(s2v), [s3]"=&v"(s3v),
              [d0]"=&v"(d0v), [d1]"=&v"(d1v), [d2]"=&v"(d2v), [d3]"=&v"(d3v),
              [e0]"=&v"(e0v), [e1]"=&v"(e1v)
            : [ps]"v"(gs), [pd]"v"(gd), [pe]"v"(ge));

        // ---- bf16-convert + wave-private LDS stage (no barrier needed) ----
        {
            const f32x4 ls[4] = {s0v, s1v, s2v, s3v};
#pragma unroll
            for (int i = 0; i < 4; ++i) {
                u16x4 p = {f2bf(ls[i].x), f2bf(ls[i].y), f2bf(ls[i].z), f2bf(ls[i].w)};
                *reinterpret_cast<u16x4*>(wsS + (i * 4 + srow) * SRC_STRIDE + scol8) = p;
            }
            const f32x4 ld[4] = {d0v, d1v, d2v, d3v};
#pragma unroll
            for (int i = 0; i < 4; ++i) {
                u16x4 p = {f2bf(ld[i].x), f2bf(ld[i].y), f2bf(ld[i].z), f2bf(ld[i].w)};
                *reinterpret_cast<u16x4*>(wsD + (i * 4 + srow) * SRC_STRIDE + scol8) = p;
            }
            const f32x4 le[2] = {e0v, e1v};
#pragma unroll
            for (int i = 0; i < 2; ++i) {
                u16x4 p = {f2bf(le[i].x), f2bf(le[i].y), f2bf(le[i].z), f2bf(le[i].w)};
                *reinterpret_cast<u16x4*>(wsE + (i * 8 + erow) * EDG_STRIDE + ecol8) = p;
            }
        }

        // ---- GEMM1 (swapped): acc[n][j] = h[row0+rr][n*16+rq*4+j], bias-init ----
        f32x4 acc[8];
#pragma unroll
        for (int n = 0; n < 8; ++n)
            acc[n] = *reinterpret_cast<const f32x4*>(&b1s[n * 16 + rq * 4]);

#pragma unroll
        for (int kk = 0; kk < 5; ++kk) {
            const char* xb; int koff, strd;
            if      (kk == 0) { xb = wsS; koff = 0;  strd = SRC_STRIDE; }
            else if (kk == 1) { xb = wsS; koff = 64; strd = SRC_STRIDE; }
            else if (kk == 2) { xb = wsD; koff = 0;  strd = SRC_STRIDE; }
            else if (kk == 3) { xb = wsD; koff = 64; strd = SRC_STRIDE; }
            else              { xb = wsE; koff = 0;  strd = EDG_STRIDE; }
            s16x8 a = *reinterpret_cast<const s16x8*>(xb + rr * strd + koff + rq * 16);

#pragma unroll
            for (int n = 0; n < 8; ++n) {
                s16x8 wv = *reinterpret_cast<const s16x8*>(&w1s[((kk * 8 + n) * 64 + lane) * 8]);
                acc[n] = __builtin_amdgcn_mfma_f32_16x16x32_bf16(wv, a, acc[n], 0, 0, 0);
            }
        }

        // ---- GEMM2: register-only h, slot bijection; w2 frags from LDS ----
        f32x4 acc2[2];
        acc2[0] = *reinterpret_cast<const f32x4*>(&b2s[(0 * 64 + lane) * 4]);
        acc2[1] = *reinterpret_cast<const f32x4*>(&b2s[(1 * 64 + lane) * 4]);

#pragma unroll
        for (int m = 0; m < 4; ++m) {
            union { s16x8 v; unsigned short u[8]; } hh;
#pragma unroll
            for (int j = 0; j < 4; ++j) {
                hh.u[j]     = f2bf(fmaxf(acc[m][j], 0.0f));      // k chunk m
                hh.u[4 + j] = f2bf(fmaxf(acc[m + 4][j], 0.0f));  // k chunk m+4
            }
            s16x8 w20 = *reinterpret_cast<const s16x8*>(&w2s[((m * 2 + 0) * 64 + lane) * 8]);
            s16x8 w21 = *reinterpret_cast<const s16x8*>(&w2s[((m * 2 + 1) * 64 + lane) * 8]);
            acc2[0] = __builtin_amdgcn_mfma_f32_16x16x32_bf16(w20, hh.v, acc2[0], 0, 0, 0);
            acc2[1] = __builtin_amdgcn_mfma_f32_16x16x32_bf16(w21, hh.v, acc2[1], 0, 0, 0);
        }

        // ---- store (R5-verified layout): lane (rq,rr) -> out[row0+rr][rq*4..] ----
        float* po = out + (row0 + rr) * 32;
        *reinterpret_cast<f32x4*>(po + rq * 4)      = acc2[0];
        *reinterpret_cast<f32x4*>(po + 16 + rq * 4) = acc2[1];
    }
}

// Scalar tail for E % 256 != 0 (not hit for E = 1,600,000; kept for safety)
__global__ void edge_mlp_tail(
    const float* __restrict__ src, const float* __restrict__ dst,
    const float* __restrict__ edg, const float* __restrict__ w1,
    const float* __restrict__ b1, const float* __restrict__ w2,
    const float* __restrict__ b2, float* __restrict__ out,
    long long row0, long long E)
{
    const long long r = row0 + blockIdx.x;
    if (r >= E) return;
    __shared__ float h[128];
    const int t = threadIdx.x;  // 128 threads
    float acc = b1[t];
    for (int k = 0; k < 64; ++k) acc += src[r * 64 + k] * w1[k * 128 + t];
    for (int k = 0; k < 64; ++k) acc += dst[r * 64 + k] * w1[(64 + k) * 128 + t];
    for (int k = 0; k < 32; ++k) acc += edg[r * 32 + k] * w1[(128 + k) * 128 + t];
    h[t] = acc > 0.0f ? acc : 0.0f;
    __syncthreads();
    if (t < 32) {
        float o = b2[t];
        for (int k = 0; k < 128; ++k) o += h[k] * w2[k * 32 + t];
        out[r * 32 + t] = o;
    }
}

extern "C" void kernel_launch(void* const* d_in, const int* in_sizes, int n_in,
                              void* d_out, int out_size, void* d_ws, size_t ws_size,
                              hipStream_t stream)
{
    const float* src = (const float*)d_in[0];
    const float* dst = (const float*)d_in[1];
    const float* edg = (const float*)d_in[2];
    // d_in[3] = u (unused), d_in[4] = batch (unused)
    const float* w1  = (const float*)d_in[5];
    const float* b1  = (const float*)d_in[6];
    const float* w2  = (const float*)d_in[7];
    const float* b2  = (const float*)d_in[8];
    float* out = (float*)d_out;

    const long long E      = (long long)in_sizes[0] / 64;
    const int       ntiles = (int)(E / 256);
    const long long rem    = E - (long long)ntiles * 256;

    if (ntiles > 0) {
        int grid = ntiles < 256 ? ntiles : 256;
        edge_mlp<<<dim3(grid), dim3(1024), 0, stream>>>(
            src, dst, edg, w1, b1, w2, b2, out, ntiles);
    }
    if (rem > 0) {
        edge_mlp_tail<<<dim3((unsigned)rem), dim3(128), 0, stream>>>(
            src, dst, edg, w1, b1, w2, b2, out, (long long)ntiles * 256, E);
    }
}